// Round 8
// baseline (115.043 us; speedup 1.0000x reference)
//
#include <hip/hip_runtime.h>
#include <math.h>
#include <string.h>

constexpr int VOCAB  = 32000;
constexpr int D      = 128;
constexpr int T      = 32;
constexpr int NCELLS = 8 * 100 * 64;   // 51200
constexpr int NCHUNK = 2;              // D split into 2 chunks of 64 dims
constexpr int CDIM   = D / NCHUNK;     // 64 dims
constexpr int ROWB   = CDIM * 2;       // 128 bytes per chunk-row (bf16)

typedef int   v4i __attribute__((ext_vector_type(4)));
typedef float v2f __attribute__((ext_vector_type(2)));

// ---- helpers
__device__ inline ushort f2bf(float f) {
    uint32_t u;
    memcpy(&u, &f, 4);
    u += 0x7FFFu + ((u >> 16) & 1u);   // RTN-even
    return (ushort)(u >> 16);
}
__device__ inline float hi16f(uint32_t b) {
    float f;
    memcpy(&f, &b, 4);
    return f;
}

// Fast exact-erf GELU: Abramowitz-Stegun 7.1.26 (|erf err| <= 1.5e-7).
__device__ inline float gelu_fast(float xv) {
    const float is2 = 0.70710678118654752440f;
    float y  = xv * is2;
    float av = fabsf(y);
    float t  = __builtin_amdgcn_rcpf(__builtin_fmaf(0.3275911f, av, 1.0f));
    float p  = 0.254829592f + t * (-0.284496736f + t * (1.421413741f
             + t * (-1.453152027f + t * 1.061405429f)));
    float e  = __expf(-av * av);
    float er = 1.0f - p * t * e;
    er = copysignf(er, y);
    return 0.5f * xv * (1.0f + er);
}

// Kernel 1: convert W_embed f32 -> bf16 chunked [chunk][vocab][CDIM], with the
// 1/T mean factor folded in (exponent-only scale: bit-exact rounding).
// Also zero-inits out.
__global__ __launch_bounds__(256) void convert_W_kernel(
    const float* __restrict__ W, ushort* __restrict__ Wb, float* __restrict__ out)
{
    const int i = blockIdx.x * blockDim.x + threadIdx.x;  // ushort4 group id
    const int v = i >> 5;        // vocab row (32 groups of 4 dims per row)
    const int k = i & 31;
    const int chunk = k >> 4;    // 16 groups (64 dims) per chunk
    const int sub   = k & 15;

    const float sc = 1.0f / (float)T;
    float4 src = reinterpret_cast<const float4*>(W)[i];
    ushort4 o;
    o.x = f2bf(src.x * sc); o.y = f2bf(src.y * sc);
    o.z = f2bf(src.z * sc); o.w = f2bf(src.w * sc);
    reinterpret_cast<ushort4*>(Wb)[(size_t)chunk * (VOCAB * 16) + (size_t)v * 16 + sub] = o;

    if (i < NCELLS) out[i] = 0.0f;
}

// Kernel 2: one wave per (cell, chunk); blockIdx%8 steers chunk to XCD halves
// so each XCD's L2 caches one 4.1 MB slice.
// Lane (q = lane>>4, h = lane&15): q picks token group {8q..8q+7}, h picks
// dim-quad 4h..4h+3 (one uint2 = 8 B per gather). 8 independent gathers/wave.
__global__ __launch_bounds__(256) void gather_kernel(
    const int*    __restrict__ x,       // [NCELLS, T]
    const ushort* __restrict__ Wb,      // [NCHUNK][VOCAB][CDIM] bf16 bits
    const float*  __restrict__ w_pred,  // [1, D]
    const float*  __restrict__ b_pred,  // [1]
    float*        __restrict__ out)     // [NCELLS] (zeroed by convert kernel)
{
    const int wave = threadIdx.x >> 6;
    const int lane = threadIdx.x & 63;

    const int slot  = blockIdx.x & 7;
    const int chunk = slot >> 2;               // 4 XCDs per chunk
    const int sub   = slot & 3;
    const int g     = blockIdx.x >> 3;         // 0..3199
    const int cell  = ((g << 2) + sub) * 4 + wave;

    const int q = lane >> 4;
    const int h = lane & 15;

    // this lane's 8 token indices: x[cell, 8q .. 8q+7], two int4 vector loads
    const v4i* xq = reinterpret_cast<const v4i*>(x + ((size_t)cell << 5)) + (q << 1);
    v4i ta = __builtin_nontemporal_load(xq);
    v4i tb = __builtin_nontemporal_load(xq + 1);
    int tok[8] = {ta.x, ta.y, ta.z, ta.w, tb.x, tb.y, tb.z, tb.w};

    const char* __restrict__ base =
        reinterpret_cast<const char*>(Wb) + (size_t)chunk * (VOCAB * ROWB);
    const uint32_t h8 = (uint32_t)(h << 3);

    // 8 independent 8B gathers (token row * 128B + h*8B)
    uint2 u[8];
    #pragma unroll
    for (int i = 0; i < 8; ++i) {
        uint32_t ob = ((uint32_t)tok[i] << 7) + h8;
        u[i] = *reinterpret_cast<const uint2*>(base + ob);
    }

    v2f A = {0.f, 0.f}, B = {0.f, 0.f};
    #pragma unroll
    for (int i = 0; i < 8; ++i) {
        v2f fa = {hi16f(u[i].x << 16), hi16f(u[i].x & 0xffff0000u)};
        v2f fb = {hi16f(u[i].y << 16), hi16f(u[i].y & 0xffff0000u)};
        A += fa;   // v_pk_add_f32
        B += fb;
    }

    // reduce across the 4 token groups (lane bits 4,5)
    A.x += __shfl_xor(A.x, 16, 64);
    A.y += __shfl_xor(A.y, 16, 64);
    B.x += __shfl_xor(B.x, 16, 64);
    B.y += __shfl_xor(B.y, 16, 64);
    A.x += __shfl_xor(A.x, 32, 64);
    A.y += __shfl_xor(A.y, 32, 64);
    B.x += __shfl_xor(B.x, 32, 64);
    B.y += __shfl_xor(B.y, 32, 64);

    // lane owns chunk-dim d = 4h + q (1/T already folded into the table)
    float v01 = (q & 1) ? A.y : A.x;
    float v23 = (q & 1) ? B.y : B.x;
    float pv  = (q & 2) ? v23 : v01;

    float gl = gelu_fast(pv);
    float wv = w_pred[chunk * CDIM + (h << 2) + q];
    float s  = gl * wv;

    #pragma unroll
    for (int o = 32; o >= 1; o >>= 1)
        s += __shfl_xor(s, o, 64);

    if (lane == 0) {
        if (chunk == 0) s += b_pred[0];
        atomicAdd(&out[cell], s);
    }
}

extern "C" void kernel_launch(void* const* d_in, const int* in_sizes, int n_in,
                              void* d_out, int out_size, void* d_ws, size_t ws_size,
                              hipStream_t stream) {
    const int*   x      = (const int*)  d_in[0];
    const float* W      = (const float*)d_in[1];
    const float* w_pred = (const float*)d_in[2];
    const float* b_pred = (const float*)d_in[3];
    float*       out    = (float*)d_out;
    ushort*      Wb     = (ushort*)d_ws;   // VOCAB*D*2 = 8.192 MB

    const int conv_groups = VOCAB * D / 4;                 // 1,024,000
    convert_W_kernel<<<conv_groups / 256, 256, 0, stream>>>(W, Wb, out);

    // 2 chunks x 12800 cell-blocks (4 cells per block) = 25600 blocks
    gather_kernel<<<NCHUNK * (NCELLS / 4), 256, 0, stream>>>(x, Wb, w_pred, b_pred, out);
}

// Round 9
// 106.488 us; speedup vs baseline: 1.0803x; 1.0803x over previous
//
#include <hip/hip_runtime.h>
#include <hip/hip_bf16.h>
#include <math.h>
#include <string.h>

constexpr int VOCAB  = 32000;
constexpr int D      = 128;
constexpr int T      = 32;
constexpr int NCELLS = 8 * 100 * 64;   // 51200
constexpr int NCHUNK = 2;              // D split into 2 chunks of 64 dims
constexpr int CDIM   = D / NCHUNK;     // 64 dims (128 B bf16 per row slice)
constexpr int CHUNK_ELEMS2 = VOCAB * (CDIM / 2);  // bf162 elems per chunk slice

// ---- helpers
__device__ inline ushort f2bf(float f) {
    uint32_t u;
    memcpy(&u, &f, 4);
    u += 0x7FFFu + ((u >> 16) & 1u);   // RTN-even
    return (ushort)(u >> 16);
}

// Fast exact-erf GELU: Abramowitz-Stegun 7.1.26 (|erf err| <= 1.5e-7).
__device__ inline float gelu_fast(float xv) {
    const float is2 = 0.70710678118654752440f;
    float y  = xv * is2;
    float av = fabsf(y);
    float t  = __builtin_amdgcn_rcpf(__builtin_fmaf(0.3275911f, av, 1.0f));
    float p  = 0.254829592f + t * (-0.284496736f + t * (1.421413741f
             + t * (-1.453152027f + t * 1.061405429f)));
    float e  = __expf(-av * av);
    float er = 1.0f - p * t * e;
    er = copysignf(er, y);
    return 0.5f * xv * (1.0f + er);
}

// Kernel 1: convert W_embed f32 -> bf16 chunked [chunk][vocab][CDIM], with the
// 1/T mean factor folded in (exponent-only scale: bit-exact rounding).
// Also zero-inits out.
__global__ __launch_bounds__(256) void convert_W_kernel(
    const float* __restrict__ W, ushort* __restrict__ Wb, float* __restrict__ out)
{
    const int i = blockIdx.x * blockDim.x + threadIdx.x;  // ushort4 group id
    const int v = i >> 5;        // vocab row (32 groups of 4 dims per row)
    const int k = i & 31;
    const int chunk = k >> 4;    // 16 groups (64 dims) per chunk
    const int sub   = k & 15;

    const float sc = 1.0f / (float)T;
    float4 src = reinterpret_cast<const float4*>(W)[i];
    ushort4 o;
    o.x = f2bf(src.x * sc); o.y = f2bf(src.y * sc);
    o.z = f2bf(src.z * sc); o.w = f2bf(src.w * sc);
    reinterpret_cast<ushort4*>(Wb)[(size_t)chunk * (VOCAB * 16) + (size_t)v * 16 + sub] = o;

    if (i < NCELLS) out[i] = 0.0f;
}

// Kernel 2: one wave per (cell, chunk); blockIdx%8 steers chunk to XCD halves
// so each XCD's L2 caches one 4.1 MB slice (measured: FETCH 311->21 MB).
// lane = (half = lane>>5, j = lane&31): per iter the wave loads 2 rows
// (tokens 2i, 2i+half), 4 B/lane (one bf162 = dims 2j,2j+1) -> exactly 2
// row-segments per instruction (measured best; 4-segment variants +8 us).
__global__ __launch_bounds__(256) void gather_kernel(
    const int*    __restrict__ x,       // [NCELLS, T]
    const ushort* __restrict__ Wb,      // [NCHUNK][VOCAB][CDIM] bf16 bits
    const float*  __restrict__ w_pred,  // [1, D]
    const float*  __restrict__ b_pred,  // [1]
    float*        __restrict__ out)     // [NCELLS] (zeroed by convert kernel)
{
    const int wave = threadIdx.x >> 6;
    const int lane = threadIdx.x & 63;

    const int slot  = blockIdx.x & 7;
    const int chunk = slot >> 2;               // 4 XCDs per chunk
    const int sub   = slot & 3;
    const int g     = blockIdx.x >> 3;         // 0..3199
    const int cell  = ((g << 2) + sub) * 4 + wave;

    const int j    = lane & 31;   // bf162 index: dims 2j, 2j+1 of chunk
    const int half = lane >> 5;

    // lane t (t = lane&31) holds token t's row offset (bf162 element units)
    int myidx  = __builtin_nontemporal_load(x + (size_t)cell * T + j);
    int rowoff = myidx << 5;      // token * 32 bf162 per row slice

    const __hip_bfloat162* __restrict__ tbl =
        reinterpret_cast<const __hip_bfloat162*>(Wb) + (size_t)chunk * CHUNK_ELEMS2;

    float ax = 0.0f, ay = 0.0f;
    #pragma unroll
    for (int i = 0; i < T / 2; ++i) {
        int e = __shfl(rowoff, 2 * i + half, 64);     // token 2i+half's row
        __hip_bfloat162 v = tbl[(uint32_t)(e + j)];   // saddr + 32b voffset
        float2 f = __bfloat1622float2(v);
        ax += f.x;
        ay += f.y;
    }
    // combine the two half-wave token subsets (even vs odd tokens)
    ax += __shfl_xor(ax, 32, 64);
    ay += __shfl_xor(ay, 32, 64);

    // lane owns chunk-dim d = 2j + half (1/T already folded into the table)
    float p  = half ? ay : ax;
    float gl = gelu_fast(p);
    float wv = w_pred[chunk * CDIM + 2 * j + half];
    float s  = gl * wv;

    #pragma unroll
    for (int off = 32; off >= 1; off >>= 1)
        s += __shfl_xor(s, off, 64);

    if (lane == 0) {
        if (chunk == 0) s += b_pred[0];
        atomicAdd(&out[cell], s);
    }
}

extern "C" void kernel_launch(void* const* d_in, const int* in_sizes, int n_in,
                              void* d_out, int out_size, void* d_ws, size_t ws_size,
                              hipStream_t stream) {
    const int*   x      = (const int*)  d_in[0];
    const float* W      = (const float*)d_in[1];
    const float* w_pred = (const float*)d_in[2];
    const float* b_pred = (const float*)d_in[3];
    float*       out    = (float*)d_out;
    ushort*      Wb     = (ushort*)d_ws;   // VOCAB*D*2 = 8.192 MB

    const int conv_groups = VOCAB * D / 4;                 // 1,024,000
    convert_W_kernel<<<conv_groups / 256, 256, 0, stream>>>(W, Wb, out);

    // 2 chunks x 12800 cell-blocks (4 cells per block) = 25600 blocks
    gather_kernel<<<NCHUNK * (NCELLS / 4), 256, 0, stream>>>(x, Wb, w_pred, b_pred, out);
}